// Round 14
// baseline (2363.401 us; speedup 1.0000x reference)
//
#include <hip/hip_runtime.h>

// ---------------------------------------------------------------------------
// TypeNet: 3 branches x (BN1 -> flattened LSTM (2048 steps) -> BN2 -> LSTM (2048 steps))
// H = 128, gates = 512. Round 14: R13 (matvec on matrix pipe, minimal VALU
// epilogue) but with 16 waves (4/SIMD) to fill the 41% matrix-pipe idle
// (MfmaUtil 0.59 -> target ~0.8). Wave w owns 8 j's via mixed-gate tiles:
// T0 rows = gates{0,1} x j's, T1 = gates{2,3}; quad q's acc regs hold ALL 8
// cells of 2 j's -> epilogue = 4 cndmask + 4 activations (no DPP collect).
// Gx chunked per-j (4 gates x 8 steps) with depth-1-chunk prefetch.
// One lgkm-only barrier per step.
// ---------------------------------------------------------------------------

typedef _Float16 half4_t __attribute__((ext_vector_type(4)));
typedef _Float16 half8 __attribute__((ext_vector_type(8)));
typedef float float4_t __attribute__((ext_vector_type(4)));

#define LOG2E 1.44269504f

__device__ __forceinline__ float fast_rcp(float x) { return __builtin_amdgcn_rcpf(x); }
__device__ __forceinline__ float exp2b(float x) { return __builtin_amdgcn_exp2f(x); }

// LDS-visibility-only barrier: no vmcnt drain (global stores/loads in flight).
__device__ __forceinline__ void lds_barrier() {
  asm volatile("s_waitcnt lgkmcnt(0)\n\ts_barrier" ::: "memory");
}

// Gx layout (half8 units): record (br, ch, j, gate) at
//   ((br*256 + ch)*128 + j)*4 + gate     -- 8 halfs = 8 steps (u = s&7).

// ---------------------------------------------------------------------------
// K1: BN1 over branch slice [128,16,3]; writes xbn[br][s=t*128+b][d].
// ---------------------------------------------------------------------------
__global__ __launch_bounds__(128) void bn1_kernel(const float* __restrict__ x,
                                                  const float* __restrict__ g1,
                                                  const float* __restrict__ b1,
                                                  float* __restrict__ xbn) {
  const int br = blockIdx.x >> 4;
  const int t  = blockIdx.x & 15;
  const int b  = threadIdx.x;
  const float* px = x + (b * 48 + br * 16 + t) * 3;
  const float v0 = px[0], v1 = px[1], v2 = px[2];
  float s  = v0 + v1 + v2;
  float ss = v0 * v0 + v1 * v1 + v2 * v2;
  for (int off = 32; off; off >>= 1) {
    s  += __shfl_down(s, off);
    ss += __shfl_down(ss, off);
  }
  __shared__ float red[4];
  if ((threadIdx.x & 63) == 0) {
    red[(threadIdx.x >> 6) * 2]     = s;
    red[(threadIdx.x >> 6) * 2 + 1] = ss;
  }
  __syncthreads();
  const float S = red[0] + red[2], SS = red[1] + red[3];
  const float mean = S * (1.0f / 384.0f);
  const float var  = SS * (1.0f / 384.0f) - mean * mean;
  const float rstd = rsqrtf(var + 1e-5f);
  const float a  = g1[t] * rstd;
  const float sh = b1[t] - mean * a;
  float* dst = xbn + br * 6144 + (t * 128 + b) * 3;
  dst[0] = v0 * a + sh;
  dst[1] = v1 * a + sh;
  dst[2] = v2 * a + sh;
}

// ---------------------------------------------------------------------------
// K1b: G1x = (Wih1 @ xbn + bih1 + bhh1) * log2e, per-j chunked layout.
// ---------------------------------------------------------------------------
__global__ __launch_bounds__(256) void g1x_kernel(const float* __restrict__ xbn,
                                                  const float* __restrict__ Wih1,
                                                  const float* __restrict__ bih1,
                                                  const float* __restrict__ bhh1,
                                                  _Float16* __restrict__ G1x) {
  const int br = blockIdx.x >> 10;
  const int sp = blockIdx.x & 1023;
  const int s  = sp * 2 + (threadIdx.x >> 7);
  const int j  = threadIdx.x & 127;
  const float* px = xbn + br * 6144 + s * 3;
  const float x0 = px[0], x1 = px[1], x2 = px[2];
  _Float16* base =
      G1x + (((size_t)(br * 256 + (s >> 3)) * 128 + j) * 4) * 8 + (s & 7);
#pragma unroll
  for (int g = 0; g < 4; ++g) {
    const int row = g * 128 + j;
    const float a = bih1[row] + bhh1[row] + Wih1[row * 3] * x0 +
                    Wih1[row * 3 + 1] * x1 + Wih1[row * 3 + 2] * x2;
    base[g * 8] = (_Float16)(a * LOG2E);
  }
}

// ---------------------------------------------------------------------------
// K3a: BN2 stats per (branch, channel) over 2048 elems of H1.
// ---------------------------------------------------------------------------
__global__ __launch_bounds__(256) void bn2stats_kernel(const float* __restrict__ H1,
                                                       float* __restrict__ stats) {
  const int br = blockIdx.x >> 7;
  const int ch = blockIdx.x & 127;
  const float* base = H1 + (size_t)br * 262144 + ch * 128;
  float s = 0.f, ss = 0.f;
  for (int k = threadIdx.x; k < 2048; k += 256) {
    const int t1 = k >> 7, h = k & 127;
    const float v = base[t1 * 16384 + h];
    s += v;
    ss += v * v;
  }
  for (int off = 32; off; off >>= 1) {
    s  += __shfl_down(s, off);
    ss += __shfl_down(ss, off);
  }
  __shared__ float red[8];
  if ((threadIdx.x & 63) == 0) {
    red[(threadIdx.x >> 6) * 2]     = s;
    red[(threadIdx.x >> 6) * 2 + 1] = ss;
  }
  __syncthreads();
  if (threadIdx.x == 0) {
    const float S  = red[0] + red[2] + red[4] + red[6];
    const float SS = red[1] + red[3] + red[5] + red[7];
    const float mean = S * (1.0f / 2048.0f);
    const float var  = SS * (1.0f / 2048.0f) - mean * mean;
    stats[(br * 128 + ch) * 2]     = mean;
    stats[(br * 128 + ch) * 2 + 1] = rsqrtf(var + 1e-5f);
  }
}

// ---------------------------------------------------------------------------
// K3b: G2x = (Wih2 @ BN2(H1) + biases) * log2e, per-j chunked layout.
// s2 = t2*16 + b2 -> ch = t2*2 + (b2>>3), u = b2&7.
// ---------------------------------------------------------------------------
__global__ __launch_bounds__(256) void g2x_kernel(
    const float* __restrict__ H1, const float* __restrict__ stats,
    const float* __restrict__ g2, const float* __restrict__ b2v,
    const float* __restrict__ Wih2, const float* __restrict__ bih2,
    const float* __restrict__ bhh2, _Float16* __restrict__ G2x) {
  const int br = blockIdx.x >> 7;
  const int t2 = blockIdx.x & 127;
  __shared__ float xh[2048];
  __shared__ float wt[64 * 129];
  const float mean = stats[(br * 128 + t2) * 2];
  const float rstd = stats[(br * 128 + t2) * 2 + 1];
  const float a  = g2[t2] * rstd;
  const float sh = b2v[t2] - mean * a;
  for (int e = threadIdx.x; e < 2048; e += 256) {
    const int b2 = e >> 7, d = e & 127;
    xh[e] = H1[(size_t)br * 262144 + (size_t)(b2 * 128 + t2) * 128 + d] * a + sh;
  }
  const int gl  = threadIdx.x & 63;
  const int b2b = (threadIdx.x >> 6) * 4;
  for (int gt = 0; gt < 8; ++gt) {
    __syncthreads();
    for (int e = threadIdx.x; e < 8192; e += 256)
      wt[(e >> 7) * 129 + (e & 127)] = Wih2[gt * 8192 + e];
    __syncthreads();
    float a0 = 0.f, a1 = 0.f, a2 = 0.f, a3 = 0.f;
    for (int d = 0; d < 128; ++d) {
      const float w = wt[gl * 129 + d];
      a0 += w * xh[(b2b + 0) * 128 + d];
      a1 += w * xh[(b2b + 1) * 128 + d];
      a2 += w * xh[(b2b + 2) * 128 + d];
      a3 += w * xh[(b2b + 3) * 128 + d];
    }
    const int g    = gt * 64 + gl;
    const int gate = g >> 7;
    const int jj   = g & 127;
    const float bb = bih2[g] + bhh2[g];
    _Float16* dst =
        G2x + (((size_t)(br * 256 + t2 * 2 + (b2b >> 3)) * 128 + jj) * 4 + gate) * 8 +
        (b2b & 7);
    *reinterpret_cast<half4_t*>(dst) =
        half4_t{(_Float16)((a0 + bb) * LOG2E), (_Float16)((a1 + bb) * LOG2E),
                (_Float16)((a2 + bb) * LOG2E), (_Float16)((a3 + bb) * LOG2E)};
  }
}

// ---------------------------------------------------------------------------
// K2/K4: the recurrence. 1 block/branch, 1024 threads (16 waves, 4/SIMD).
// Wave w owns j in [8w, 8w+8). Tile T0 row r: gate=(r>>1)&1,
// j = 8w + 2*(r>>2) + (r&1); T1 = gates {2,3} same j map. Quad q's acc regs:
// accT[0..3] = {gate(2T) j=2q, gate(2T) j=2q+1, gate(2T+1) j=2q, ... j=2q+1}.
// Lane (quad q, jp=l15&1) owns j = 8w + 2q + jp: its 4 gate values are
// accT[jp] / accT[2+jp] -> 4 cndmask. 8 MFMAs/wave/step. l15<2 lanes write
// h + out. Gx: 4 half8 loads per 8-step chunk, waited one chunk later.
// One lgkm-only barrier per step.
// ---------------------------------------------------------------------------
__global__ __launch_bounds__(1024, 4) void lstm_kernel(
    const float* __restrict__ Whh, const float* __restrict__ h0s,
    const float* __restrict__ c0s, const _Float16* __restrict__ Gx,
    float* __restrict__ outp, int layer) {
  const int br   = blockIdx.x;
  const int tid  = threadIdx.x;
  const int wave = tid >> 6;
  const int lane = tid & 63;
  const int quad = lane >> 4;
  const int l15  = lane & 15;
  const int jp   = l15 & 1;
  const int j    = wave * 8 + 2 * quad + jp;  // this lane's h index
  const bool store = (l15 < 2);

  __shared__ __align__(16) _Float16 h_sh[2][128];

  // ---- preload Whh as f16 A-fragments (log2e-prescaled), mixed-gate tiles ----
  half8 afrag[2][4];
  {
    const int rg = (l15 >> 1) & 1;
    const int rj = wave * 8 + 2 * (l15 >> 2) + (l15 & 1);
#pragma unroll
    for (int t = 0; t < 2; ++t) {
      const int row = (t * 2 + rg) * 128 + rj;
#pragma unroll
      for (int kt = 0; kt < 4; ++kt) {
        const float* src = Whh + row * 128 + kt * 32 + quad * 8;
        half8 f;
#pragma unroll
        for (int jj = 0; jj < 8; ++jj) f[jj] = (_Float16)(src[jj] * LOG2E);
        afrag[t][kt] = f;
      }
    }
  }

  const int slot = 2 * br + layer;
  float c = c0s[slot * 128 + j];  // lanes sharing j hold identical c
  if (tid < 128) h_sh[0][tid] = (_Float16)h0s[slot * 128 + tid];

  // Gx chunk stream: 4 gate-records (half8 each) per (chunk, j)
  const half8* gq = (const half8*)Gx;
  size_t gb = ((size_t)(br * 256) * 128 + j) * 4;
  half8 cur0 = gq[gb], cur1 = gq[gb + 1], cur2 = gq[gb + 2], cur3 = gq[gb + 3];
  float* op = outp + (size_t)br * 262144 + j;

  const float4_t zacc = {0.f, 0.f, 0.f, 0.f};
  __syncthreads();  // once; full drain fine

  for (int ch = 0; ch < 256; ++ch) {
    const int chn = (ch < 255) ? ch + 1 : 255;
    const size_t nb = ((size_t)(br * 256 + chn) * 128 + j) * 4;
    const half8 n0 = gq[nb], n1 = gq[nb + 1], n2 = gq[nb + 2], n3 = gq[nb + 3];

#pragma unroll
    for (int u = 0; u < 8; ++u) {
      // B fragments: every lane supplies h[k] -> every D column is the matvec
      const _Float16* hcur = h_sh[u & 1];
      half8 bfrag[4];
#pragma unroll
      for (int kt = 0; kt < 4; ++kt)
        bfrag[kt] = *reinterpret_cast<const half8*>(&hcur[kt * 32 + quad * 8]);

      // 2 independent MFMA chains (one per tile), zero-C first MFMA
      float4_t acc0 = __builtin_amdgcn_mfma_f32_16x16x32_f16(afrag[0][0], bfrag[0],
                                                             zacc, 0, 0, 0);
      float4_t acc1 = __builtin_amdgcn_mfma_f32_16x16x32_f16(afrag[1][0], bfrag[0],
                                                             zacc, 0, 0, 0);
#pragma unroll
      for (int kt = 1; kt < 4; ++kt) {
        acc0 = __builtin_amdgcn_mfma_f32_16x16x32_f16(afrag[0][kt], bfrag[kt],
                                                      acc0, 0, 0, 0);
        acc1 = __builtin_amdgcn_mfma_f32_16x16x32_f16(afrag[1][kt], bfrag[kt],
                                                      acc1, 0, 0, 0);
      }

      const float p0 = (float)cur0[u];
      const float p1 = (float)cur1[u];
      const float p2 = (float)cur2[u];
      const float p3 = (float)cur3[u];

      // 1-of-2 j select per gate (4 cndmask), + log2e-scaled preact
      const float gi = (jp ? acc0[1] : acc0[0]) + p0;
      const float gf = (jp ? acc0[3] : acc0[2]) + p1;
      const float gg = (jp ? acc1[1] : acc1[0]) + p2;
      const float go = (jp ? acc1[3] : acc1[2]) + p3;

      const float iv = fast_rcp(1.0f + exp2b(-gi));
      const float fv = fast_rcp(1.0f + exp2b(-gf));
      const float gv = __builtin_fmaf(-2.0f, fast_rcp(1.0f + exp2b(gg + gg)), 1.0f);
      const float ov = fast_rcp(1.0f + exp2b(-go));
      c = fv * c + iv * gv;
      const float t  = __builtin_fmaf(
          -2.0f, fast_rcp(1.0f + exp2b(c * 2.88539008f)), 1.0f);
      const float hv = ov * t;

      if (store) {
        h_sh[(u + 1) & 1][j] = (_Float16)hv;
        *op = hv;
      }
      op += 128;
      lds_barrier();  // h broadcast; lgkm-only
    }

    cur0 = n0; cur1 = n1; cur2 = n2; cur3 = n3;  // vmcnt wait lands here
  }
}

// ---------------------------------------------------------------------------
// Workspace layout (floats):
//   xbn   [3][2048][3]            @ 0        (18432)
//   H1    [3][2048][128]          @ 18432    (786432)
//   stats [3][128][2]             @ 804864   (768)
//   G1x   chunked f16             @ 805632   (1572864 floats)
//   G2x   chunked f16             @ 2378496  (1572864 floats)   total ~15.8 MB
// ---------------------------------------------------------------------------
extern "C" void kernel_launch(void* const* d_in, const int* in_sizes, int n_in,
                              void* d_out, int out_size, void* d_ws, size_t ws_size,
                              hipStream_t stream) {
  const float* x    = (const float*)d_in[0];
  const float* g1   = (const float*)d_in[1];
  const float* b1   = (const float*)d_in[2];
  const float* Wih1 = (const float*)d_in[3];
  const float* Whh1 = (const float*)d_in[4];
  const float* bih1 = (const float*)d_in[5];
  const float* bhh1 = (const float*)d_in[6];
  const float* g2   = (const float*)d_in[7];
  const float* b2   = (const float*)d_in[8];
  const float* Wih2 = (const float*)d_in[9];
  const float* Whh2 = (const float*)d_in[10];
  const float* bih2 = (const float*)d_in[11];
  const float* bhh2 = (const float*)d_in[12];
  const float* h0s  = (const float*)d_in[13];
  const float* c0s  = (const float*)d_in[14];

  float* ws   = (float*)d_ws;
  float* xbn  = ws;
  float* H1b  = ws + 18432;
  float* st   = ws + 18432 + 786432;
  _Float16* G1xb = (_Float16*)(ws + 805632);
  _Float16* G2xb = (_Float16*)(ws + 2378496);
  float* outp = (float*)d_out;

  bn1_kernel<<<48, 128, 0, stream>>>(x, g1, b1, xbn);
  g1x_kernel<<<3072, 256, 0, stream>>>(xbn, Wih1, bih1, bhh1, G1xb);
  lstm_kernel<<<3, 1024, 0, stream>>>(Whh1, h0s, c0s, G1xb, H1b, 0);
  bn2stats_kernel<<<384, 256, 0, stream>>>(H1b, st);
  g2x_kernel<<<384, 256, 0, stream>>>(H1b, st, g2, b2, Wih2, bih2, bhh2, G2xb);
  lstm_kernel<<<3, 1024, 0, stream>>>(Whh2, h0s, c0s, G2xb, outp, 1);
}

// Round 16
// 1540.345 us; speedup vs baseline: 1.5343x; 1.5343x over previous
//
#include <hip/hip_runtime.h>

// ---------------------------------------------------------------------------
// TypeNet: 3 branches x (BN1 -> flattened LSTM (2048 steps) -> BN2 -> LSTM (2048 steps))
// H = 128, gates = 512. Round 16: R15's i8 MFMA recurrence (mfma_i32_16x16x64,
// 64 MFMAs/step -> ~326 cyc MFMA phase vs f16's 620) + two precision fixes
// for R15's 2.73e-2 fail: (1) EXACT f32 step-0 preact per owned cell
// (computed once at init; step-0 MFMA result discarded -> h0 quant error
// gone), (2) noise-shaped h quantization (error-feedback residual ->
// first-difference quant noise, attenuated by the LSTM's forget-gate
// low-pass). Epilogue/barrier structure unchanged from R13/R15.
// ---------------------------------------------------------------------------

typedef _Float16 half4_t __attribute__((ext_vector_type(4)));
typedef _Float16 half8 __attribute__((ext_vector_type(8)));
typedef float float4_t __attribute__((ext_vector_type(4)));
typedef int int4_t __attribute__((ext_vector_type(4)));

#define LOG2E 1.44269504f

__device__ __forceinline__ float fast_rcp(float x) { return __builtin_amdgcn_rcpf(x); }
__device__ __forceinline__ float exp2b(float x) { return __builtin_amdgcn_exp2f(x); }

// DPP quad broadcast: lane PAT of each aligned 4-lane group to all 4.
#define QBCAST(x, pat)                                                        \
  __int_as_float(__builtin_amdgcn_update_dpp(0, __float_as_int(x), (pat),     \
                                             0xF, 0xF, true))

// LDS-visibility-only barrier: no vmcnt drain (global stores/loads in flight).
__device__ __forceinline__ void lds_barrier() {
  asm volatile("s_waitcnt lgkmcnt(0)\n\ts_barrier" ::: "memory");
}

// Gx record index for (j, gate): ridx = (j>>4)*64 + ((j>>2)&3)*16 + (j&3)*4 + gate
__host__ __device__ __forceinline__ int ridx0_of(int j) {
  return (j >> 4) * 64 + ((j >> 2) & 3) * 16 + (j & 3) * 4;
}

// ---------------------------------------------------------------------------
// K1: BN1 over branch slice [128,16,3]; writes xbn[br][s=t*128+b][d].
// ---------------------------------------------------------------------------
__global__ __launch_bounds__(128) void bn1_kernel(const float* __restrict__ x,
                                                  const float* __restrict__ g1,
                                                  const float* __restrict__ b1,
                                                  float* __restrict__ xbn) {
  const int br = blockIdx.x >> 4;
  const int t  = blockIdx.x & 15;
  const int b  = threadIdx.x;
  const float* px = x + (b * 48 + br * 16 + t) * 3;
  const float v0 = px[0], v1 = px[1], v2 = px[2];
  float s  = v0 + v1 + v2;
  float ss = v0 * v0 + v1 * v1 + v2 * v2;
  for (int off = 32; off; off >>= 1) {
    s  += __shfl_down(s, off);
    ss += __shfl_down(ss, off);
  }
  __shared__ float red[4];
  if ((threadIdx.x & 63) == 0) {
    red[(threadIdx.x >> 6) * 2]     = s;
    red[(threadIdx.x >> 6) * 2 + 1] = ss;
  }
  __syncthreads();
  const float S = red[0] + red[2], SS = red[1] + red[3];
  const float mean = S * (1.0f / 384.0f);
  const float var  = SS * (1.0f / 384.0f) - mean * mean;
  const float rstd = rsqrtf(var + 1e-5f);
  const float a  = g1[t] * rstd;
  const float sh = b1[t] - mean * a;
  float* dst = xbn + br * 6144 + (t * 128 + b) * 3;
  dst[0] = v0 * a + sh;
  dst[1] = v1 * a + sh;
  dst[2] = v2 * a + sh;
}

// ---------------------------------------------------------------------------
// K1b: G1x = (Wih1 @ xbn + bih1 + bhh1) * log2e, chunked layout w/ ridx map.
// ---------------------------------------------------------------------------
__global__ __launch_bounds__(256) void g1x_kernel(const float* __restrict__ xbn,
                                                  const float* __restrict__ Wih1,
                                                  const float* __restrict__ bih1,
                                                  const float* __restrict__ bhh1,
                                                  _Float16* __restrict__ G1x) {
  const int br = blockIdx.x >> 10;
  const int sp = blockIdx.x & 1023;
  const int s  = sp * 2 + (threadIdx.x >> 7);
  const int j  = threadIdx.x & 127;
  const float* px = xbn + br * 6144 + s * 3;
  const float x0 = px[0], x1 = px[1], x2 = px[2];
  _Float16* base =
      G1x + ((size_t)(br * 128 + (s >> 4)) * 512 + ridx0_of(j)) * 16 + (s & 15);
#pragma unroll
  for (int g = 0; g < 4; ++g) {
    const int row = g * 128 + j;
    const float a = bih1[row] + bhh1[row] + Wih1[row * 3] * x0 +
                    Wih1[row * 3 + 1] * x1 + Wih1[row * 3 + 2] * x2;
    base[g * 16] = (_Float16)(a * LOG2E);
  }
}

// ---------------------------------------------------------------------------
// K3a: BN2 stats per (branch, channel) over 2048 elems of H1.
// ---------------------------------------------------------------------------
__global__ __launch_bounds__(256) void bn2stats_kernel(const float* __restrict__ H1,
                                                       float* __restrict__ stats) {
  const int br = blockIdx.x >> 7;
  const int ch = blockIdx.x & 127;
  const float* base = H1 + (size_t)br * 262144 + ch * 128;
  float s = 0.f, ss = 0.f;
  for (int k = threadIdx.x; k < 2048; k += 256) {
    const int t1 = k >> 7, h = k & 127;
    const float v = base[t1 * 16384 + h];
    s += v;
    ss += v * v;
  }
  for (int off = 32; off; off >>= 1) {
    s  += __shfl_down(s, off);
    ss += __shfl_down(ss, off);
  }
  __shared__ float red[8];
  if ((threadIdx.x & 63) == 0) {
    red[(threadIdx.x >> 6) * 2]     = s;
    red[(threadIdx.x >> 6) * 2 + 1] = ss;
  }
  __syncthreads();
  if (threadIdx.x == 0) {
    const float S  = red[0] + red[2] + red[4] + red[6];
    const float SS = red[1] + red[3] + red[5] + red[7];
    const float mean = S * (1.0f / 2048.0f);
    const float var  = SS * (1.0f / 2048.0f) - mean * mean;
    stats[(br * 128 + ch) * 2]     = mean;
    stats[(br * 128 + ch) * 2 + 1] = rsqrtf(var + 1e-5f);
  }
}

// ---------------------------------------------------------------------------
// K3b: G2x = (Wih2 @ BN2(H1) + biases) * log2e, chunked layout w/ ridx map.
// ---------------------------------------------------------------------------
__global__ __launch_bounds__(256) void g2x_kernel(
    const float* __restrict__ H1, const float* __restrict__ stats,
    const float* __restrict__ g2, const float* __restrict__ b2v,
    const float* __restrict__ Wih2, const float* __restrict__ bih2,
    const float* __restrict__ bhh2, _Float16* __restrict__ G2x) {
  const int br = blockIdx.x >> 7;
  const int t2 = blockIdx.x & 127;
  __shared__ float xh[2048];
  __shared__ float wt[64 * 129];
  const float mean = stats[(br * 128 + t2) * 2];
  const float rstd = stats[(br * 128 + t2) * 2 + 1];
  const float a  = g2[t2] * rstd;
  const float sh = b2v[t2] - mean * a;
  for (int e = threadIdx.x; e < 2048; e += 256) {
    const int b2 = e >> 7, d = e & 127;
    xh[e] = H1[(size_t)br * 262144 + (size_t)(b2 * 128 + t2) * 128 + d] * a + sh;
  }
  const int gl  = threadIdx.x & 63;
  const int b2b = (threadIdx.x >> 6) * 4;
  for (int gt = 0; gt < 8; ++gt) {
    __syncthreads();
    for (int e = threadIdx.x; e < 8192; e += 256)
      wt[(e >> 7) * 129 + (e & 127)] = Wih2[gt * 8192 + e];
    __syncthreads();
    float a0 = 0.f, a1 = 0.f, a2 = 0.f, a3 = 0.f;
    for (int d = 0; d < 128; ++d) {
      const float w = wt[gl * 129 + d];
      a0 += w * xh[(b2b + 0) * 128 + d];
      a1 += w * xh[(b2b + 1) * 128 + d];
      a2 += w * xh[(b2b + 2) * 128 + d];
      a3 += w * xh[(b2b + 3) * 128 + d];
    }
    const int g    = gt * 64 + gl;
    const int gate = g >> 7;
    const int jj   = g & 127;
    const int ri   = ridx0_of(jj) + gate;
    const float bb = bih2[g] + bhh2[g];
    _Float16* dst = G2x + ((size_t)(br * 128 + t2) * 512 + ri) * 16 + b2b;
    *reinterpret_cast<half4_t*>(dst) =
        half4_t{(_Float16)((a0 + bb) * LOG2E), (_Float16)((a1 + bb) * LOG2E),
                (_Float16)((a2 + bb) * LOG2E), (_Float16)((a3 + bb) * LOG2E)};
  }
}

// ---------------------------------------------------------------------------
// K2/K4: the recurrence. 1 block/branch, 512 threads (8 waves, 2/SIMD).
// i8 MFMA 16x16x64: wave w owns one 16-row m-tile per gate; 8 MFMAs/wave/step.
// Step 0 preact computed EXACTLY in f32 at init (overrides MFMA result).
// h quantized with error feedback (noise shaping). Epilogue: one cell per
// lane (l15 = rr*4+gate), int selects, unified activation, 4 QBCAST.
// One lgkm-only barrier per step. Gx: 2 half8 loads / 16-step chunk.
// ---------------------------------------------------------------------------
__global__ __launch_bounds__(512, 1) void lstm_kernel(
    const float* __restrict__ Whh, const float* __restrict__ h0s,
    const float* __restrict__ c0s, const _Float16* __restrict__ Gx,
    float* __restrict__ outp, int layer) {
  const int br   = blockIdx.x;
  const int tid  = threadIdx.x;
  const int wave = tid >> 6;
  const int lane = tid & 63;
  const int quad = lane >> 4;
  const int l15  = lane & 15;
  const int gate = l15 & 3;
  const int rr   = l15 >> 2;
  const int j    = wave * 16 + quad * 4 + rr;  // this lane's cell row
  const bool rb0 = (rr & 1) != 0;
  const bool rb1 = (rr & 2) != 0;
  const bool gb0 = (gate & 1) != 0;
  const bool gb1 = (gate & 2) != 0;
  // unified activation: sigm (i,f,o): s=1,B=1; tanh (g): s=2,B=2
  const float scg = (gate == 2) ? 2.0f : 1.0f;
  const float Bcg = (gate == 2) ? 2.0f : 1.0f;

  __shared__ __align__(16) signed char h_sh[2][128];
  __shared__ float rowscale[512];
  __shared__ __align__(16) float h0f[128];

  // ---- quantize Whh to i8 A-fragments (per-row scale), 4 gates x 2 k ----
  int4_t afrag[4][2];
#pragma unroll
  for (int g = 0; g < 4; ++g) {
    const int row = g * 128 + wave * 16 + l15;
    const float4_t* wr = (const float4_t*)(Whh + row * 128);
    float m = 1e-8f;
    for (int k4 = 0; k4 < 32; ++k4) {
      const float4_t v = wr[k4];
      m = fmaxf(m, fmaxf(fmaxf(fabsf(v[0]), fabsf(v[1])),
                         fmaxf(fabsf(v[2]), fabsf(v[3]))));
    }
    if (quad == 0) rowscale[row] = m;
    const float inv = 127.0f / m;
#pragma unroll
    for (int t = 0; t < 2; ++t) {
      int4_t f;
#pragma unroll
      for (int w = 0; w < 4; ++w) {
        int word = 0;
#pragma unroll
        for (int b = 0; b < 4; ++b) {
          const int k = t * 64 + quad * 16 + w * 4 + b;
          const int q = (int)__builtin_rintf(Whh[row * 128 + k] * inv);
          word |= (q & 255) << (8 * b);
        }
        f[w] = word;
      }
      afrag[g][t] = f;
    }
  }

  const int slot = 2 * br + layer;
  float c = c0s[slot * 128 + j];  // 4 gate-lanes per j hold identical c
  if (tid < 128) {
    const float h0 = h0s[slot * 128 + tid];
    h0f[tid] = h0;
    // i8 encoding of h0 is irrelevant (step-0 MFMA result is overridden);
    // clip for sanity.
    float qf = __builtin_rintf(h0 * 127.0f);
    qf = fminf(fmaxf(qf, -127.0f), 127.0f);
    h_sh[0][tid] = (signed char)(int)qf;
  }

  // Gx chunk stream: record = 16 halfs at ((br*128+ch)*512 + tid)*16
  const half8* gq = (const half8*)Gx;
  half8 curA = gq[((size_t)(br * 128) * 512 + tid) * 2];
  half8 curB = gq[((size_t)(br * 128) * 512 + tid) * 2 + 1];
  float* op = outp + (size_t)br * 262144 + j;

  const int4_t zi = {0, 0, 0, 0};
  __syncthreads();  // publishes rowscale + h0f

  // dequant scale for this lane's owned cell row (log2e folded in)
  const float s_own = rowscale[gate * 128 + j] * (LOG2E / (127.0f * 127.0f));

  // ---- EXACT f32 step-0 preact for the owned cell (one-time) ----
  float exact0;
  {
    const int rowo = gate * 128 + j;
    const float4_t* wr4 = (const float4_t*)(Whh + rowo * 128);
    const float4_t* h04 = (const float4_t*)h0f;
    float e0 = 0.f, e1 = 0.f;
#pragma unroll 8
    for (int k4 = 0; k4 < 32; k4 += 2) {
      const float4_t a0 = wr4[k4],     b0 = h04[k4];
      const float4_t a1 = wr4[k4 + 1], b1 = h04[k4 + 1];
      e0 = __builtin_fmaf(a0[0], b0[0], e0);
      e0 = __builtin_fmaf(a0[1], b0[1], e0);
      e0 = __builtin_fmaf(a0[2], b0[2], e0);
      e0 = __builtin_fmaf(a0[3], b0[3], e0);
      e1 = __builtin_fmaf(a1[0], b1[0], e1);
      e1 = __builtin_fmaf(a1[1], b1[1], e1);
      e1 = __builtin_fmaf(a1[2], b1[2], e1);
      e1 = __builtin_fmaf(a1[3], b1[3], e1);
    }
    exact0 = (e0 + e1) * LOG2E;
  }

  float qres = 0.f;  // noise-shaping residual (store lanes)

  for (int chk = 0; chk < 128; ++chk) {
    const int chn = (chk < 127) ? chk + 1 : 127;
    const size_t nrec = ((size_t)(br * 128 + chn) * 512 + tid) * 2;
    const half8 nA = gq[nrec], nB = gq[nrec + 1];  // waited at chunk end

#pragma unroll
    for (int u = 0; u < 16; ++u) {
      // B fragments: 16 i8 per lane per k-half (same addr per quad -> bcast)
      const signed char* hs = h_sh[u & 1];
      const int4_t b0 = *(const int4_t*)(hs + quad * 16);
      const int4_t b1 = *(const int4_t*)(hs + 64 + quad * 16);

      const float pre = (float)((u < 8) ? curA[u] : curB[u - 8]);

      // 4 independent i8 MFMA chains (one per gate), depth 2
      int4_t acc[4];
#pragma unroll
      for (int g = 0; g < 4; ++g)
        acc[g] = __builtin_amdgcn_mfma_i32_16x16x64_i8(afrag[g][0], b0, zi, 0, 0, 0);
#pragma unroll
      for (int g = 0; g < 4; ++g)
        acc[g] = __builtin_amdgcn_mfma_i32_16x16x64_i8(afrag[g][1], b1, acc[g], 0, 0, 0);

      // int selects: element rr of each gate's acc, then own gate
      int e0, e1, e2, e3;
      {
        int x, y;
        x = rb0 ? acc[0][1] : acc[0][0]; y = rb0 ? acc[0][3] : acc[0][2];
        e0 = rb1 ? y : x;
        x = rb0 ? acc[1][1] : acc[1][0]; y = rb0 ? acc[1][3] : acc[1][2];
        e1 = rb1 ? y : x;
        x = rb0 ? acc[2][1] : acc[2][0]; y = rb0 ? acc[2][3] : acc[2][2];
        e2 = rb1 ? y : x;
        x = rb0 ? acc[3][1] : acc[3][0]; y = rb0 ? acc[3][3] : acc[3][2];
        e3 = rb1 ? y : x;
      }
      const int eA = gb0 ? e1 : e0;
      const int eB = gb0 ? e3 : e2;
      const int ei = gb1 ? eB : eA;

      float a = __builtin_fmaf((float)ei, s_own, pre);
      if (u == 0 && chk == 0) a = exact0 + pre;  // exact step 0 (no h0 quant)

      // unified activation: 1 - B*rcp(1 + exp2(s*a))
      const float act = __builtin_fmaf(-Bcg, fast_rcp(1.0f + exp2b(scg * a)), 1.0f);

      // collect the 4 gates across the aligned 4-lane group
      const float iv = QBCAST(act, 0x00);
      const float fv = QBCAST(act, 0x55);
      const float gv = QBCAST(act, 0xAA);
      const float ov = QBCAST(act, 0xFF);

      c = fv * c + iv * gv;
      const float t  = __builtin_fmaf(
          -2.0f, fast_rcp(1.0f + exp2b(c * 2.88539008f)), 1.0f);
      const float hv = ov * t;

      if (gate == 0) {
        // noise-shaped quantization: carry rounding error to next step
        const float hq = hv + qres;
        float qf = __builtin_rintf(hq * 127.0f);
        qf = fminf(fmaxf(qf, -127.0f), 127.0f);
        qres = __builtin_fmaf(qf, -(1.0f / 127.0f), hq);
        h_sh[(u + 1) & 1][j] = (signed char)(int)qf;
        *op = hv;  // output keeps full precision
      }
      op += 128;
      lds_barrier();  // h broadcast; lgkm-only
    }

    curA = nA;  // vmcnt wait lands here, one full chunk after issue
    curB = nB;
  }
}

// ---------------------------------------------------------------------------
// Workspace layout (floats):
//   xbn   [3][2048][3]            @ 0        (18432)
//   H1    [3][2048][128]          @ 18432    (786432)
//   stats [3][128][2]             @ 804864   (768)
//   G1x   chunked f16             @ 805632   (1572864 floats)
//   G2x   chunked f16             @ 2378496  (1572864 floats)   total ~15.8 MB
// ---------------------------------------------------------------------------
extern "C" void kernel_launch(void* const* d_in, const int* in_sizes, int n_in,
                              void* d_out, int out_size, void* d_ws, size_t ws_size,
                              hipStream_t stream) {
  const float* x    = (const float*)d_in[0];
  const float* g1   = (const float*)d_in[1];
  const float* b1   = (const float*)d_in[2];
  const float* Wih1 = (const float*)d_in[3];
  const float* Whh1 = (const float*)d_in[4];
  const float* bih1 = (const float*)d_in[5];
  const float* bhh1 = (const float*)d_in[6];
  const float* g2   = (const float*)d_in[7];
  const float* b2   = (const float*)d_in[8];
  const float* Wih2 = (const float*)d_in[9];
  const float* Whh2 = (const float*)d_in[10];
  const float* bih2 = (const float*)d_in[11];
  const float* bhh2 = (const float*)d_in[12];
  const float* h0s  = (const float*)d_in[13];
  const float* c0s  = (const float*)d_in[14];

  float* ws   = (float*)d_ws;
  float* xbn  = ws;
  float* H1b  = ws + 18432;
  float* st   = ws + 18432 + 786432;
  _Float16* G1xb = (_Float16*)(ws + 805632);
  _Float16* G2xb = (_Float16*)(ws + 2378496);
  float* outp = (float*)d_out;

  bn1_kernel<<<48, 128, 0, stream>>>(x, g1, b1, xbn);
  g1x_kernel<<<3072, 256, 0, stream>>>(xbn, Wih1, bih1, bhh1, G1xb);
  lstm_kernel<<<3, 512, 0, stream>>>(Whh1, h0s, c0s, G1xb, H1b, 0);
  bn2stats_kernel<<<384, 256, 0, stream>>>(H1b, st);
  g2x_kernel<<<384, 256, 0, stream>>>(H1b, st, g2, b2, Wih2, bih2, bhh2, G2xb);
  lstm_kernel<<<3, 512, 0, stream>>>(Whh2, h0s, c0s, G2xb, outp, 1);
}